// Round 1
// baseline (58.574 us; speedup 1.0000x reference)
//
#include <hip/hip_runtime.h>

// QuantumLayer: n=8 qubits, RY(x) layer + RY(w) layer + CNOT chain (0->1 ... 6->7),
// measure <Z> on qubit 0 (most significant bit).
//
// Analytic collapse:
//   - product state after both RY layers: qubit q amplitude [cos(th/2), sin(th/2)],
//     th = x[b,q] + w[q]  (RY angles compose on the same qubit)
//   - CNOT chain never targets qubit 0 => P(bit0) invariant
//   - out[b] = cos^2(th0/2) - sin^2(th0/2) = cos(x[b,0] + w[0])
//
// Perf shape: timed region = harness 256 MiB workspace poison fill (~41.5 us,
// untouchable) + this kernel. Kernel floor: 8 MB forced fetch of x (col-0 at
// 32 B stride touches every cache line) + 1 MB write ~= 1.5 us @ 6.3 TB/s.
// This version: 4 outputs/thread -> 4x fewer waves, ILP-4 independent loads
// (hides cold-HBM latency ~900 cyc), single coalesced float4 store.

#define BATCH 262144
#define N_QUBITS 8

__global__ __launch_bounds__(256) void qlayer_cos_kernel(
    const float* __restrict__ x,      // [B, 8]
    const float* __restrict__ w,      // [8]
    float* __restrict__ out,          // [B]
    int B)
{
    const float w0 = w[0];                       // uniform scalar load + broadcast
    int t = blockIdx.x * blockDim.x + threadIdx.x;
    int b = t * 4;                               // 4 consecutive rows per thread
    if (b + 3 < B) {
        // 4 independent column-0 loads, 32 B apart (span one 128 B segment).
        // Issued back-to-back: 4 outstanding VMEM ops/lane before first use.
        float x0 = x[(size_t)(b + 0) * N_QUBITS];
        float x1 = x[(size_t)(b + 1) * N_QUBITS];
        float x2 = x[(size_t)(b + 2) * N_QUBITS];
        float x3 = x[(size_t)(b + 3) * N_QUBITS];

        float4 r;
        r.x = cosf(x0 + w0);
        r.y = cosf(x1 + w0);
        r.z = cosf(x2 + w0);
        r.w = cosf(x3 + w0);

        // One 16 B fully-coalesced store per lane (1 KiB per wave).
        *reinterpret_cast<float4*>(out + b) = r;
    } else {
        // tail guard (not hit at B=262144, kept for safety)
        for (int i = b; i < B && i < b + 4; ++i) {
            out[i] = cosf(x[(size_t)i * N_QUBITS] + w0);
        }
    }
}

extern "C" void kernel_launch(void* const* d_in, const int* in_sizes, int n_in,
                              void* d_out, int out_size, void* d_ws, size_t ws_size,
                              hipStream_t stream) {
    const float* x = (const float*)d_in[0];   // [262144, 8] fp32
    const float* w = (const float*)d_in[1];   // [8] fp32
    float* out = (float*)d_out;               // [262144] fp32

    const int B = out_size;                   // 262144
    const int block = 256;
    const int threads = (B + 3) / 4;          // 65536 threads, 4 outputs each
    const int grid = (threads + block - 1) / block;  // 256 blocks

    qlayer_cos_kernel<<<grid, block, 0, stream>>>(x, w, out, B);
}

// Round 2
// 55.919 us; speedup vs baseline: 1.0475x; 1.0475x over previous
//
#include <hip/hip_runtime.h>

// QuantumLayer: n=8 qubits, RY(x) layer + RY(w) layer + CNOT chain (0->1 ... 6->7),
// measure <Z> on qubit 0 (most significant bit).
//
// Analytic collapse:
//   - product state after both RY layers: qubit q amplitude [cos(th/2), sin(th/2)],
//     th = x[b,q] + w[q]  (RY angles compose on the same qubit)
//   - CNOT chain never targets qubit 0 => P(bit0) invariant
//   - out[b] = cos^2(th0/2) - sin^2(th0/2) = cos(x[b,0] + w[0])
//
// Perf shape (rounds 0-1 evidence): timed region = harness 256 MiB poison
// fill (~41.5 us @ 81% HBM peak, untouchable) + ~15 us of reset/dispatch
// overhead + this kernel (~1.5-3 us: 8 MB forced fetch of x since col-0 at
// 32 B stride touches every line, + 1 MB write). An ILP-4 / float4-store
// restructure (R1) measured +1.8 us: cold-HBM latency here is hidden by
// wave count (TLP), not per-lane ILP, and 1-row/thread keeps the wave's
// access span at 2 KB/instruction (best coalescing the layout allows).
// This is the best harness-verified variant: 56.78 us.

#define BATCH 262144
#define N_QUBITS 8

__global__ __launch_bounds__(256) void qlayer_cos_kernel(
    const float* __restrict__ x,      // [B, 8]
    const float* __restrict__ w,      // [8]
    float* __restrict__ out,          // [B]
    int B)
{
    const float w0 = w[0];            // uniform: scalar-loaded + broadcast
    int b = blockIdx.x * blockDim.x + threadIdx.x;
    if (b < B) {
        float x0 = x[(size_t)b * N_QUBITS];   // column 0, stride-8 read
        out[b] = cosf(x0 + w0);
    }
}

extern "C" void kernel_launch(void* const* d_in, const int* in_sizes, int n_in,
                              void* d_out, int out_size, void* d_ws, size_t ws_size,
                              hipStream_t stream) {
    const float* x = (const float*)d_in[0];   // [262144, 8] fp32
    const float* w = (const float*)d_in[1];   // [8] fp32
    float* out = (float*)d_out;               // [262144] fp32

    const int B = out_size;                   // 262144
    const int block = 256;
    const int grid = (B + block - 1) / block; // 1024 blocks

    qlayer_cos_kernel<<<grid, block, 0, stream>>>(x, w, out, B);
}